// Round 1
// baseline (968.881 us; speedup 1.0000x reference)
//
#include <hip/hip_runtime.h>
#include <math.h>

#define TSTEPS 288
#define NTHREADS 512

__device__ __forceinline__ float sigmoidf_(float x) {
    return 1.0f / (1.0f + __expf(-x));
}

// One workgroup processes ONE batch sample for ONE layer's full scan.
// Combined matvec z = [x_t, h_{t-1}] @ [W; U] + b, columns distributed
// across threads, combined-weight columns held in registers.
//   DIN: input width, U: units, NSPLIT: k-split factor (512/(4U)),
//   INOFF: column offset of the input inside a seq row (64 for layer 1,
//          where x was preloaded into seq[t][64..128)), 0 otherwise.
template<int DIN, int U, int NSPLIT, int INOFF, bool WRITE_SEQ>
__device__ void run_layer(const float* __restrict__ W,
                          const float* __restrict__ Uw,
                          const float* __restrict__ bias,
                          float* __restrict__ seq,
                          float* __restrict__ xh,
                          float* __restrict__ zbuf,
                          int tid)
{
    constexpr int COLS = 4 * U;
    constexpr int ROWS = DIN + U;
    constexpr int KSEG = ROWS / NSPLIT;   // rows handled by this thread's segment
    const int col = tid % COLS;
    const int seg = tid / COLS;

    // --- load this thread's combined-weight column segment into registers ---
    float wreg[KSEG];
#pragma unroll
    for (int k = 0; k < KSEG; ++k) {
        const int row = seg * KSEG + k;
        wreg[k] = (row < DIN) ? W[row * COLS + col]
                              : Uw[(row - DIN) * COLS + col];
    }
    const float biasreg = (seg == 0) ? bias[col] : 0.0f;

    // --- init xh = [input(0), h=0] ---
    if (tid < DIN) xh[tid] = seq[0 * 128 + INOFF + tid];
    if (tid >= DIN && tid < ROWS) xh[tid] = 0.0f;
    float c = 0.0f;
    __syncthreads();

    for (int t = 0; t < TSTEPS; ++t) {
        // ---- phase B: z_col partial = dot(xh[seg range], wreg) ----
        float a0 = biasreg, a1 = 0.0f, a2 = 0.0f, a3 = 0.0f;
        const float4* xv = reinterpret_cast<const float4*>(xh + seg * KSEG);
#pragma unroll
        for (int k4 = 0; k4 < KSEG / 4; ++k4) {
            const float4 v = xv[k4];   // wave-uniform address -> LDS broadcast
            a0 = fmaf(v.x, wreg[4 * k4 + 0], a0);
            a1 = fmaf(v.y, wreg[4 * k4 + 1], a1);
            a2 = fmaf(v.z, wreg[4 * k4 + 2], a2);
            a3 = fmaf(v.w, wreg[4 * k4 + 3], a3);
        }
        zbuf[tid] = (a0 + a1) + (a2 + a3);
        __syncthreads();

        // ---- phase C: gate update (threads < U) ∥ phase A: stage next input ----
        if (tid < U) {
            float zi = zbuf[tid];
            float zf = zbuf[U + tid];
            float zg = zbuf[2 * U + tid];
            float zo = zbuf[3 * U + tid];
#pragma unroll
            for (int s = 1; s < NSPLIT; ++s) {
                zi += zbuf[s * COLS + tid];
                zf += zbuf[s * COLS + U + tid];
                zg += zbuf[s * COLS + 2 * U + tid];
                zo += zbuf[s * COLS + 3 * U + tid];
            }
            const float gi = sigmoidf_(zi);
            const float gf = sigmoidf_(zf);
            const float gg = fmaxf(zg, 0.0f);         // cell activation = relu
            const float go = sigmoidf_(zo);
            c = fmaf(gf, c, gi * gg);
            const float h = go * fmaxf(c, 0.0f);      // output activation = relu
            xh[DIN + tid] = h;
            if (WRITE_SEQ) seq[t * 128 + tid] = h;
        } else if (tid >= U && tid < U + DIN) {
            const int k = tid - U;
            if (t + 1 < TSTEPS) xh[k] = seq[(t + 1) * 128 + INOFF + k];
        }
        __syncthreads();
    }
}

extern "C" __global__ void __launch_bounds__(NTHREADS, 2)
lstm_stack_kernel(const float* __restrict__ x,
                  const float* __restrict__ W1, const float* __restrict__ U1, const float* __restrict__ b1,
                  const float* __restrict__ W2, const float* __restrict__ U2, const float* __restrict__ b2,
                  const float* __restrict__ W3, const float* __restrict__ U3, const float* __restrict__ b3,
                  const float* __restrict__ W4, const float* __restrict__ U4, const float* __restrict__ b4,
                  const float* __restrict__ Wf, const float* __restrict__ bf,
                  const float* __restrict__ Wo, const float* __restrict__ bo,
                  float* __restrict__ out)
{
    // seq[t][0..127]: hidden sequence of the current layer (in-place across layers)
    // x[b] preloaded into seq[t][64..127] for layer 1.
    __shared__ __align__(16) float seq[TSTEPS * 128];
    __shared__ __align__(16) float xh[192];
    __shared__ __align__(16) float zbuf[NTHREADS];

    const int tid = threadIdx.x;
    const int b = blockIdx.x;

    // ---- preload x[b] (288x64 fp32, contiguous) into seq[t][64..128) ----
    const float4* xb = reinterpret_cast<const float4*>(x + (size_t)b * TSTEPS * 64);
#pragma unroll
    for (int i = 0; i < (TSTEPS * 64 / 4) / NTHREADS; ++i) {
        const int g = tid + i * NTHREADS;   // float4 index within sample
        const int t = g / 16;               // 16 float4 per 64-float row
        const int f4 = g % 16;
        reinterpret_cast<float4*>(seq + t * 128 + 64)[f4] = xb[g];
    }
    __syncthreads();

    run_layer< 64, 128, 1, 64, true >(W1, U1, b1, seq, xh, zbuf, tid);
    run_layer<128,  64, 2,  0, true >(W2, U2, b2, seq, xh, zbuf, tid);
    run_layer< 64,  64, 2,  0, true >(W3, U3, b3, seq, xh, zbuf, tid);
    run_layer< 64,  32, 4,  0, false>(W4, U4, b4, seq, xh, zbuf, tid);

    // ---- FC head: h4_last lives in xh[64..96) ----
    if (tid < 16) {
        float acc = bf[tid];
#pragma unroll
        for (int k = 0; k < 32; ++k) acc = fmaf(xh[64 + k], Wf[k * 16 + tid], acc);
        zbuf[tid] = fmaxf(acc, 0.0f);
    }
    __syncthreads();
    if (tid == 0) {
        float acc = bo[0];
#pragma unroll
        for (int k = 0; k < 16; ++k) acc = fmaf(zbuf[k], Wo[k], acc);
        out[b] = acc;
    }
}

extern "C" void kernel_launch(void* const* d_in, const int* in_sizes, int n_in,
                              void* d_out, int out_size, void* d_ws, size_t ws_size,
                              hipStream_t stream) {
    const float* x  = (const float*)d_in[0];
    const float* W1 = (const float*)d_in[1];
    const float* U1 = (const float*)d_in[2];
    const float* b1 = (const float*)d_in[3];
    const float* W2 = (const float*)d_in[4];
    const float* U2 = (const float*)d_in[5];
    const float* b2 = (const float*)d_in[6];
    const float* W3 = (const float*)d_in[7];
    const float* U3 = (const float*)d_in[8];
    const float* b3 = (const float*)d_in[9];
    const float* W4 = (const float*)d_in[10];
    const float* U4 = (const float*)d_in[11];
    const float* b4 = (const float*)d_in[12];
    const float* Wf = (const float*)d_in[13];
    const float* bf = (const float*)d_in[14];
    const float* Wo = (const float*)d_in[15];
    const float* bo = (const float*)d_in[16];
    float* out = (float*)d_out;

    lstm_stack_kernel<<<dim3(256), dim3(NTHREADS), 0, stream>>>(
        x, W1, U1, b1, W2, U2, b2, W3, U3, b3, W4, U4, b4, Wf, bf, Wo, bo, out);
}

// Round 2
// 775.248 us; speedup vs baseline: 1.2498x; 1.2498x over previous
//
#include <hip/hip_runtime.h>
#include <math.h>

#define TSTEPS 288
#define NTHREADS 1024

__device__ __forceinline__ float sigmoidf_(float x) {
    return 1.0f / (1.0f + __expf(-x));
}

// Sum over aligned quads of lanes (seg bits 0..1 after xor1, bit ... ) via DPP
// quad_perm — VALU pipe, no LDS traffic. After this, every lane holds the sum
// over its 4-lane quad; lanes with (seg&3)==0 write the quad partial.
__device__ __forceinline__ float quad_reduce(float v) {
    v += __int_as_float(__builtin_amdgcn_update_dpp(
            0, __float_as_int(v), 0xB1, 0xF, 0xF, true));   // quad_perm [1,0,3,2] : xor 1
    v += __int_as_float(__builtin_amdgcn_update_dpp(
            0, __float_as_int(v), 0x4E, 0xF, 0xF, true));   // quad_perm [2,3,0,1] : xor 2
    return v;
}

// One block = one sample. Combined matvec z = [x_t, h] @ [Wk; Wr] + b.
// Thread (cg, seg): cg = tid/NSPLIT handles C adjacent columns, seg = tid%NSPLIT
// handles KIN input rows + KH hidden rows. Weights register-resident.
// Cross-seg reduce: DPP over seg quads, then NSPLIT/4 LDS partials per column.
template<int DIN, int U, int C, int NSPLIT, bool FIRST, bool WRITE_SEQ>
__device__ void run_layer(const float* __restrict__ Wk,
                          const float* __restrict__ Wr,
                          const float* __restrict__ bias,
                          const float* __restrict__ xg,   // x + b*T*64 (FIRST only)
                          float* __restrict__ seq,
                          float* __restrict__ xh,
                          float* __restrict__ zbuf,
                          float* __restrict__ xring,
                          int tid)
{
    constexpr int COLS = 4 * U;
    constexpr int NCG  = COLS / C;
    constexpr int KIN  = DIN / NSPLIT;
    constexpr int KH   = U / NSPLIT;
    constexpr int NRED = NSPLIT / 4;
    static_assert(NCG * NSPLIT == NTHREADS, "thread mapping must cover block");
    static_assert(KIN % 4 == 0 && KH % 4 == 0, "float4 alignment");

    const int cg   = tid / NSPLIT;
    const int seg  = tid % NSPLIT;
    const int col0 = cg * C;

    // ---- register-resident weight column segments (loaded once per layer) ----
    float wreg[C][KIN + KH];
#pragma unroll
    for (int c = 0; c < C; ++c) {
#pragma unroll
        for (int k = 0; k < KIN; ++k)
            wreg[c][k] = Wk[(seg * KIN + k) * COLS + col0 + c];
#pragma unroll
        for (int k = 0; k < KH; ++k)
            wreg[c][KIN + k] = Wr[(seg * KH + k) * COLS + col0 + c];
    }

    float bz[4];
    if (tid < U) {
#pragma unroll
        for (int g = 0; g < 4; ++g) bz[g] = bias[g * U + tid];
    }
    if (tid < 128) xh[tid] = 0.0f;
    float cst = 0.0f;

    float4 xreg = make_float4(0.f, 0.f, 0.f, 0.f);
    if (FIRST) {
        if (tid < 128) xring[tid] = xg[tid];              // rows 0,1 of x
        if (tid >= 512 && tid < 528)                      // prefetch row 2
            xreg = reinterpret_cast<const float4*>(xg)[2 * 16 + (tid - 512)];
    }
    __syncthreads();

    for (int t = 0; t < TSTEPS; ++t) {
        // ---------- phase B: per-thread partial matvec ----------
        const float* in = FIRST ? (xring + (t & 3) * 64) : (seq + t * 128);
        float a[C];
#pragma unroll
        for (int c = 0; c < C; ++c) a[c] = 0.0f;

        const float4* in4 = reinterpret_cast<const float4*>(in + seg * KIN);
#pragma unroll
        for (int k4 = 0; k4 < KIN / 4; ++k4) {
            const float4 v = in4[k4];
#pragma unroll
            for (int c = 0; c < C; ++c) {
                a[c] = fmaf(v.x, wreg[c][4 * k4 + 0], a[c]);
                a[c] = fmaf(v.y, wreg[c][4 * k4 + 1], a[c]);
                a[c] = fmaf(v.z, wreg[c][4 * k4 + 2], a[c]);
                a[c] = fmaf(v.w, wreg[c][4 * k4 + 3], a[c]);
            }
        }
        const float4* h4 = reinterpret_cast<const float4*>(xh + seg * KH);
#pragma unroll
        for (int k4 = 0; k4 < KH / 4; ++k4) {
            const float4 v = h4[k4];
#pragma unroll
            for (int c = 0; c < C; ++c) {
                a[c] = fmaf(v.x, wreg[c][KIN + 4 * k4 + 0], a[c]);
                a[c] = fmaf(v.y, wreg[c][KIN + 4 * k4 + 1], a[c]);
                a[c] = fmaf(v.z, wreg[c][KIN + 4 * k4 + 2], a[c]);
                a[c] = fmaf(v.w, wreg[c][KIN + 4 * k4 + 3], a[c]);
            }
        }
#pragma unroll
        for (int c = 0; c < C; ++c) a[c] = quad_reduce(a[c]);

        if ((seg & 3) == 0) {
            if constexpr (C == 4) {
                *reinterpret_cast<float4*>(&zbuf[(seg >> 2) * COLS + col0]) =
                    make_float4(a[0], a[1], a[2], a[3]);
            } else {
                zbuf[(seg >> 2) * COLS + col0] = a[0];
            }
        }
        __syncthreads();

        // ---------- phase C: gate update ∥ L1 input ring staging ----------
        if (tid < U) {
            float z[4];
#pragma unroll
            for (int g = 0; g < 4; ++g) {
                float s = bz[g];
#pragma unroll
                for (int r = 0; r < NRED; ++r) s += zbuf[r * COLS + g * U + tid];
                z[g] = s;
            }
            const float gi = sigmoidf_(z[0]);
            const float gf = sigmoidf_(z[1]);
            const float gg = fmaxf(z[2], 0.0f);           // cell activation = relu
            const float go = sigmoidf_(z[3]);
            cst = fmaf(gf, cst, gi * gg);
            const float h = go * fmaxf(cst, 0.0f);        // output activation = relu
            xh[tid] = h;
            if (WRITE_SEQ) seq[t * 128 + tid] = h;
        } else if (FIRST && tid >= 512 && tid < 528) {
            const int j = tid - 512;
            if (t + 2 < TSTEPS)
                reinterpret_cast<float4*>(xring + ((t + 2) & 3) * 64)[j] = xreg;
            if (t + 3 < TSTEPS)
                xreg = reinterpret_cast<const float4*>(xg)[(t + 3) * 16 + j];
        }
        __syncthreads();
    }
}

extern "C" __global__ void __launch_bounds__(NTHREADS)
lstm_stack_kernel(const float* __restrict__ x,
                  const float* __restrict__ W1, const float* __restrict__ U1, const float* __restrict__ b1,
                  const float* __restrict__ W2, const float* __restrict__ U2, const float* __restrict__ b2,
                  const float* __restrict__ W3, const float* __restrict__ U3, const float* __restrict__ b3,
                  const float* __restrict__ W4, const float* __restrict__ U4, const float* __restrict__ b4,
                  const float* __restrict__ Wf, const float* __restrict__ bf,
                  const float* __restrict__ Wo, const float* __restrict__ bo,
                  float* __restrict__ out)
{
    __shared__ __align__(16) float seq[TSTEPS * 128];   // 147456 B
    __shared__ __align__(16) float zbuf[1024];          //   4096 B
    __shared__ __align__(16) float xh[128];             //    512 B
    __shared__ __align__(16) float xring[4 * 64];       //   1024 B

    const int tid = threadIdx.x;
    const float* xg = x + (size_t)blockIdx.x * TSTEPS * 64;

    //                 DIN   U  C NSPLIT FIRST WRITE_SEQ
    run_layer< 64, 128, 4,  8, true , true >(W1, U1, b1, xg, seq, xh, zbuf, xring, tid);
    run_layer<128,  64, 4, 16, false, true >(W2, U2, b2, xg, seq, xh, zbuf, xring, tid);
    run_layer< 64,  64, 4, 16, false, true >(W3, U3, b3, xg, seq, xh, zbuf, xring, tid);
    run_layer< 64,  32, 1,  8, false, false>(W4, U4, b4, xg, seq, xh, zbuf, xring, tid);

    // ---- FC head: h4_last in xh[0..32) ----
    if (tid < 16) {
        float acc = bf[tid];
#pragma unroll
        for (int k = 0; k < 32; ++k) acc = fmaf(xh[k], Wf[k * 16 + tid], acc);
        zbuf[tid] = fmaxf(acc, 0.0f);
    }
    __syncthreads();
    if (tid == 0) {
        float acc = bo[0];
#pragma unroll
        for (int k = 0; k < 16; ++k) acc = fmaf(zbuf[k], Wo[k], acc);
        out[blockIdx.x] = acc;
    }
}

extern "C" void kernel_launch(void* const* d_in, const int* in_sizes, int n_in,
                              void* d_out, int out_size, void* d_ws, size_t ws_size,
                              hipStream_t stream) {
    const float* x  = (const float*)d_in[0];
    const float* W1 = (const float*)d_in[1];
    const float* U1 = (const float*)d_in[2];
    const float* b1 = (const float*)d_in[3];
    const float* W2 = (const float*)d_in[4];
    const float* U2 = (const float*)d_in[5];
    const float* b2 = (const float*)d_in[6];
    const float* W3 = (const float*)d_in[7];
    const float* U3 = (const float*)d_in[8];
    const float* b3 = (const float*)d_in[9];
    const float* W4 = (const float*)d_in[10];
    const float* U4 = (const float*)d_in[11];
    const float* b4 = (const float*)d_in[12];
    const float* Wf = (const float*)d_in[13];
    const float* bf = (const float*)d_in[14];
    const float* Wo = (const float*)d_in[15];
    const float* bo = (const float*)d_in[16];
    float* out = (float*)d_out;

    lstm_stack_kernel<<<dim3(256), dim3(NTHREADS), 0, stream>>>(
        x, W1, U1, b1, W2, U2, b2, W3, U3, b3, W4, U4, b4, Wf, bf, Wo, bo, out);
}